// Round 1
// baseline (296.561 us; speedup 1.0000x reference)
//
#include <hip/hip_runtime.h>

// Problem constants: B=2, L=2048, DIM=1024, H=16, HD=64, scale=1/8, MASK_SCALE=-60
#define LL 2048
#define NHEADS 16
#define HDIM 64

typedef __attribute__((ext_vector_type(8))) __bf16 bf16x8;
typedef __attribute__((ext_vector_type(4))) float f32x4;

__device__ __forceinline__ unsigned short f2bf(float f) {
  unsigned int u = __builtin_bit_cast(unsigned int, f);
  u += 0x7fffu + ((u >> 16) & 1u);   // round-to-nearest-even
  return (unsigned short)(u >> 16);
}

__device__ __forceinline__ bf16x8 ld_frag(const unsigned short* p) {
  return *reinterpret_cast<const bf16x8*>(p);
}

// ---------------- prep: fp32 -> bf16 convert of x ----------------
__global__ __launch_bounds__(256) void cvt_x_kernel(const float* __restrict__ x,
                                                    unsigned short* __restrict__ xb) {
  int i = (blockIdx.x * 256 + threadIdx.x) * 4;
  float4 v = *reinterpret_cast<const float4*>(x + i);
  ushort4 o;
  o.x = f2bf(v.x); o.y = f2bf(v.y); o.z = f2bf(v.z); o.w = f2bf(v.w);
  *reinterpret_cast<ushort4*>(xb + i) = o;
}

// ---------------- prep: W [K][N] fp32 -> Wt [N][K] bf16 (per z in {q,k,v}) ----------------
__global__ __launch_bounds__(256) void transpose_w_kernel(const float* __restrict__ Wq,
                                                          const float* __restrict__ Wk,
                                                          const float* __restrict__ Wv,
                                                          unsigned short* __restrict__ WtAll) {
  int z = blockIdx.z;
  const float* W = (z == 0) ? Wq : (z == 1) ? Wk : Wv;
  unsigned short* dst = WtAll + (size_t)z * 1024 * 1024;
  int n0 = blockIdx.x * 64, k0 = blockIdx.y * 64;
  __shared__ float t[64][65];
  int tx = threadIdx.x & 63, ty = threadIdx.x >> 6;
#pragma unroll
  for (int p = 0; p < 16; ++p) {
    int kr = p * 4 + ty;
    t[kr][tx] = W[(size_t)(k0 + kr) * 1024 + n0 + tx];
  }
  __syncthreads();
#pragma unroll
  for (int p = 0; p < 16; ++p) {
    int nr = p * 4 + ty;
    dst[(size_t)(n0 + nr) * 1024 + k0 + tx] = f2bf(t[tx][nr]);
  }
}

// ---------------- QKV projection GEMM ----------------
// grid (8, 32, 3): x = N-tile (128), y = M-tile (128), z = weight {q,k,v}
// C[m][n] = sum_k xb[m][k] * W[k][n] + bias[n], written to [B,H,L,HD] bf16
__global__ __launch_bounds__(256) void qkv_gemm_kernel(
    const unsigned short* __restrict__ xb, const unsigned short* __restrict__ WtAll,
    const float* __restrict__ bq, const float* __restrict__ bk, const float* __restrict__ bv,
    unsigned short* __restrict__ qkv) {
  const int z = blockIdx.z;
  const unsigned short* Wt = WtAll + (size_t)z * 1024 * 1024;
  const float* bias = (z == 0) ? bq : (z == 1) ? bk : bv;
  unsigned short* outb = qkv + (size_t)z * 4194304;

  __shared__ __align__(16) unsigned short As[128 * 72];
  __shared__ __align__(16) unsigned short Bs[128 * 72];

  const int tid = threadIdx.x;
  const int w = tid >> 6, lane = tid & 63, g = lane >> 4, cc = lane & 15;
  const int wm = w >> 1, wn = w & 1;
  const int m0 = blockIdx.y * 128, n0 = blockIdx.x * 128;
  const int lr = tid >> 3, lc = (tid & 7) * 8;

  f32x4 acc[4][4];
#pragma unroll
  for (int i = 0; i < 4; ++i)
#pragma unroll
    for (int j = 0; j < 4; ++j) acc[i][j] = (f32x4)0.0f;

  for (int kk = 0; kk < 1024; kk += 64) {
    __syncthreads();
#pragma unroll
    for (int p = 0; p < 4; ++p) {
      int row = p * 32 + lr;
      *reinterpret_cast<uint4*>(&As[row * 72 + lc]) =
          *reinterpret_cast<const uint4*>(xb + (size_t)(m0 + row) * 1024 + kk + lc);
      *reinterpret_cast<uint4*>(&Bs[row * 72 + lc]) =
          *reinterpret_cast<const uint4*>(Wt + (size_t)(n0 + row) * 1024 + kk + lc);
    }
    __syncthreads();
    bf16x8 af[4][2], bfr[4][2];
#pragma unroll
    for (int mt = 0; mt < 4; ++mt)
#pragma unroll
      for (int ks = 0; ks < 2; ++ks)
        af[mt][ks] = ld_frag(&As[(wm * 64 + mt * 16 + cc) * 72 + ks * 32 + g * 8]);
#pragma unroll
    for (int nt = 0; nt < 4; ++nt)
#pragma unroll
      for (int ks = 0; ks < 2; ++ks)
        bfr[nt][ks] = ld_frag(&Bs[(wn * 64 + nt * 16 + cc) * 72 + ks * 32 + g * 8]);
#pragma unroll
    for (int mt = 0; mt < 4; ++mt)
#pragma unroll
      for (int nt = 0; nt < 4; ++nt)
#pragma unroll
        for (int ks = 0; ks < 2; ++ks)
          acc[mt][nt] = __builtin_amdgcn_mfma_f32_16x16x32_bf16(af[mt][ks], bfr[nt][ks],
                                                                acc[mt][nt], 0, 0, 0);
  }

#pragma unroll
  for (int nt = 0; nt < 4; ++nt) {
    int n = n0 + wn * 64 + nt * 16 + cc;
    float bval = bias[n];
    int h = n >> 6, d = n & 63;
#pragma unroll
    for (int mt = 0; mt < 4; ++mt) {
#pragma unroll
      for (int r = 0; r < 4; ++r) {
        int m = m0 + wm * 64 + mt * 16 + g * 4 + r;
        int b = m >> 11, l = m & 2047;
        outb[(((size_t)(b * NHEADS + h) * LL) + l) * HDIM + d] = f2bf(acc[mt][nt][r] + bval);
      }
    }
  }
}

// ---------------- flash attention ----------------
// grid (16, 32): x = q-tile (128 rows), y = b*16+h. 256 threads = 4 waves,
// wave w owns q rows [w*32, w*32+32) of the tile (2 MFMA m-tiles).
__global__ __launch_bounds__(256) void flash_kernel(
    const unsigned short* __restrict__ Qb, const unsigned short* __restrict__ Kb,
    const unsigned short* __restrict__ Vb, const float* __restrict__ mask,
    float* __restrict__ out) {
  const int bh = blockIdx.y, b = bh >> 4, h = bh & 15;
  const int q0 = blockIdx.x * 128;
  const int tid = threadIdx.x, w = tid >> 6, lane = tid & 63, g = lane >> 4, cc = lane & 15;
  const size_t bhoff = (size_t)bh * LL * HDIM;

  __shared__ __align__(16) unsigned short Qs[128 * 72];  // Q tile; reused as P after frag load
  __shared__ __align__(16) unsigned short Ks[64 * 72];   // K tile [key][d]
  __shared__ __align__(16) unsigned short Vs[64 * 72];   // V tile transposed [d][key]

  const int lr = tid >> 3, lc = (tid & 7) * 8;
#pragma unroll
  for (int p = 0; p < 4; ++p) {
    int row = p * 32 + lr;
    *reinterpret_cast<uint4*>(&Qs[row * 72 + lc]) =
        *reinterpret_cast<const uint4*>(Qb + bhoff + (size_t)(q0 + row) * HDIM + lc);
  }
  __syncthreads();
  bf16x8 aq[2][2];
#pragma unroll
  for (int mt = 0; mt < 2; ++mt)
#pragma unroll
    for (int ks = 0; ks < 2; ++ks)
      aq[mt][ks] = ld_frag(&Qs[(w * 32 + mt * 16 + cc) * 72 + ks * 32 + g * 8]);

  float mi[2][4], li[2][4];
  f32x4 oacc[2][4];
#pragma unroll
  for (int mt = 0; mt < 2; ++mt) {
#pragma unroll
    for (int r = 0; r < 4; ++r) { mi[mt][r] = -3.0e38f; li[mt][r] = 0.0f; }
#pragma unroll
    for (int nt = 0; nt < 4; ++nt) oacc[mt][nt] = (f32x4)0.0f;
  }

  for (int kt = 0; kt < 32; ++kt) {
    __syncthreads();  // previous iteration's LDS reads done before restaging
    // stage K tile
#pragma unroll
    for (int p = 0; p < 2; ++p) {
      int row = p * 32 + lr;
      *reinterpret_cast<uint4*>(&Ks[row * 72 + lc]) =
          *reinterpret_cast<const uint4*>(Kb + bhoff + (size_t)(kt * 64 + row) * HDIM + lc);
    }
    // stage V tile transposed: Vs[d][key] (coalesced row reads, packed b32 writes)
#pragma unroll
    for (int yy = 0; yy < 8; ++yy) {
      int kp = yy * 8 + w * 2;
      unsigned int v0 = Vb[bhoff + (size_t)(kt * 64 + kp) * HDIM + lane];
      unsigned int v1 = Vb[bhoff + (size_t)(kt * 64 + kp + 1) * HDIM + lane];
      *reinterpret_cast<unsigned int*>(&Vs[lane * 72 + kp]) = v0 | (v1 << 16);
    }
    __syncthreads();

    // S = Q @ K^T  (per wave: 32 q-rows x 64 keys)
    bf16x8 bk_[4][2];
#pragma unroll
    for (int nt = 0; nt < 4; ++nt)
#pragma unroll
      for (int ks = 0; ks < 2; ++ks)
        bk_[nt][ks] = ld_frag(&Ks[(nt * 16 + cc) * 72 + ks * 32 + g * 8]);
    f32x4 sacc[2][4];
#pragma unroll
    for (int mt = 0; mt < 2; ++mt)
#pragma unroll
      for (int nt = 0; nt < 4; ++nt) sacc[mt][nt] = (f32x4)0.0f;
#pragma unroll
    for (int mt = 0; mt < 2; ++mt)
#pragma unroll
      for (int nt = 0; nt < 4; ++nt)
#pragma unroll
        for (int ks = 0; ks < 2; ++ks)
          sacc[mt][nt] = __builtin_amdgcn_mfma_f32_16x16x32_bf16(aq[mt][ks], bk_[nt][ks],
                                                                 sacc[mt][nt], 0, 0, 0);

    // online softmax; P written (bf16) into recycled Qs region (wave-private rows)
#pragma unroll
    for (int mt = 0; mt < 2; ++mt) {
#pragma unroll
      for (int r = 0; r < 4; ++r) {
        int qrow = q0 + w * 32 + mt * 16 + g * 4 + r;
        const float* mrow = mask + ((size_t)b * LL + qrow) * LL + kt * 64 + cc;
        float s0 = sacc[mt][0][r] * 0.125f + mrow[0]  * -60.0f;
        float s1 = sacc[mt][1][r] * 0.125f + mrow[16] * -60.0f;
        float s2 = sacc[mt][2][r] * 0.125f + mrow[32] * -60.0f;
        float s3 = sacc[mt][3][r] * 0.125f + mrow[48] * -60.0f;
        float vm = fmaxf(fmaxf(s0, s1), fmaxf(s2, s3));
        vm = fmaxf(vm, __shfl_xor(vm, 1));
        vm = fmaxf(vm, __shfl_xor(vm, 2));
        vm = fmaxf(vm, __shfl_xor(vm, 4));
        vm = fmaxf(vm, __shfl_xor(vm, 8));
        float mold = mi[mt][r];
        float mnew = fmaxf(mold, vm);
        float al = __expf(mold - mnew);
        mi[mt][r] = mnew;
        float p0 = __expf(s0 - mnew), p1 = __expf(s1 - mnew);
        float p2 = __expf(s2 - mnew), p3 = __expf(s3 - mnew);
        float sum = p0 + p1 + p2 + p3;
        sum += __shfl_xor(sum, 1);
        sum += __shfl_xor(sum, 2);
        sum += __shfl_xor(sum, 4);
        sum += __shfl_xor(sum, 8);
        li[mt][r] = li[mt][r] * al + sum;
#pragma unroll
        for (int nt = 0; nt < 4; ++nt) oacc[mt][nt][r] *= al;
        int prow = (w * 32 + mt * 16 + g * 4 + r) * 72 + cc;
        Qs[prow]      = f2bf(p0);
        Qs[prow + 16] = f2bf(p1);
        Qs[prow + 32] = f2bf(p2);
        Qs[prow + 48] = f2bf(p3);
      }
    }
    __syncthreads();  // P visible for A-layout frag reads

    // O = diag(alpha)*O + P @ V
    bf16x8 ap[2][2], bvv[4][2];
#pragma unroll
    for (int mt = 0; mt < 2; ++mt)
#pragma unroll
      for (int ks = 0; ks < 2; ++ks)
        ap[mt][ks] = ld_frag(&Qs[(w * 32 + mt * 16 + cc) * 72 + ks * 32 + g * 8]);
#pragma unroll
    for (int nt = 0; nt < 4; ++nt)
#pragma unroll
      for (int ks = 0; ks < 2; ++ks)
        bvv[nt][ks] = ld_frag(&Vs[(nt * 16 + cc) * 72 + ks * 32 + g * 8]);
#pragma unroll
    for (int mt = 0; mt < 2; ++mt)
#pragma unroll
      for (int nt = 0; nt < 4; ++nt)
#pragma unroll
        for (int ks = 0; ks < 2; ++ks)
          oacc[mt][nt] = __builtin_amdgcn_mfma_f32_16x16x32_bf16(ap[mt][ks], bvv[nt][ks],
                                                                 oacc[mt][nt], 0, 0, 0);
  }

  // epilogue: normalize and write [B, L, H*HD] fp32
#pragma unroll
  for (int mt = 0; mt < 2; ++mt)
#pragma unroll
    for (int r = 0; r < 4; ++r) {
      int qrow = q0 + w * 32 + mt * 16 + g * 4 + r;
      float inv = 1.0f / li[mt][r];
#pragma unroll
      for (int nt = 0; nt < 4; ++nt)
        out[((size_t)b * LL + qrow) * 1024 + h * 64 + nt * 16 + cc] = oacc[mt][nt][r] * inv;
    }
}

extern "C" void kernel_launch(void* const* d_in, const int* in_sizes, int n_in,
                              void* d_out, int out_size, void* d_ws, size_t ws_size,
                              hipStream_t stream) {
  const float* x    = (const float*)d_in[0];
  const float* mask = (const float*)d_in[1];
  const float* Wq   = (const float*)d_in[2];
  const float* bq   = (const float*)d_in[3];
  const float* Wk   = (const float*)d_in[4];
  const float* bk   = (const float*)d_in[5];
  const float* Wv   = (const float*)d_in[6];
  const float* bv   = (const float*)d_in[7];
  float* out = (float*)d_out;

  char* ws = (char*)d_ws;
  unsigned short* xb  = (unsigned short*)(ws);                      // 8 MiB: x as bf16 [4096][1024]
  unsigned short* Wt  = (unsigned short*)(ws + (8u << 20));         // 6 MiB: Wq,Wk,Wv transposed bf16
  unsigned short* qkv = (unsigned short*)(ws + (14u << 20));        // 24 MiB: Q,K,V bf16 [BH][L][HD]

  cvt_x_kernel<<<dim3(4096), dim3(256), 0, stream>>>(x, xb);
  transpose_w_kernel<<<dim3(16, 16, 3), dim3(256), 0, stream>>>(Wq, Wk, Wv, Wt);
  qkv_gemm_kernel<<<dim3(8, 32, 3), dim3(256), 0, stream>>>(xb, Wt, bq, bk, bv, qkv);
  flash_kernel<<<dim3(16, 32), dim3(256), 0, stream>>>(qkv, qkv + 4194304, qkv + 8388608,
                                                       mask, out);
}

// Round 2
// 253.245 us; speedup vs baseline: 1.1710x; 1.1710x over previous
//
#include <hip/hip_runtime.h>

// Problem constants: B=2, L=2048, DIM=1024, H=16, HD=64
// scale folded into Q: 0.125*log2(e); mask coef: -60*log2(e); softmax via exp2, no max-sub
#define LL 2048
#define NHEADS 16
#define HDIM 64
#define QSCALE 0.18033688011112042f   // 0.125 * log2(e)
#define MASKC1 -86.56170245333780f    // -60 * log2(e)

typedef __attribute__((ext_vector_type(8))) __bf16 bf16x8;
typedef __attribute__((ext_vector_type(4))) float f32x4;

__device__ __forceinline__ unsigned short f2bf(float f) {
  unsigned int u = __builtin_bit_cast(unsigned int, f);
  u += 0x7fffu + ((u >> 16) & 1u);   // round-to-nearest-even
  return (unsigned short)(u >> 16);
}

__device__ __forceinline__ bf16x8 ld_frag(const unsigned short* p) {
  return *reinterpret_cast<const bf16x8*>(p);
}

// ---------------- prep: fp32 -> bf16 convert of x ----------------
__global__ __launch_bounds__(256) void cvt_x_kernel(const float* __restrict__ x,
                                                    unsigned short* __restrict__ xb) {
  int i = (blockIdx.x * 256 + threadIdx.x) * 4;
  float4 v = *reinterpret_cast<const float4*>(x + i);
  ushort4 o;
  o.x = f2bf(v.x); o.y = f2bf(v.y); o.z = f2bf(v.z); o.w = f2bf(v.w);
  *reinterpret_cast<ushort4*>(xb + i) = o;
}

// ---------------- prep: W [K][N] fp32 -> Wt [N][K] bf16 (per z in {q,k,v}) ----------------
__global__ __launch_bounds__(256) void transpose_w_kernel(const float* __restrict__ Wq,
                                                          const float* __restrict__ Wk,
                                                          const float* __restrict__ Wv,
                                                          unsigned short* __restrict__ WtAll) {
  int z = blockIdx.z;
  const float* W = (z == 0) ? Wq : (z == 1) ? Wk : Wv;
  unsigned short* dst = WtAll + (size_t)z * 1024 * 1024;
  int n0 = blockIdx.x * 64, k0 = blockIdx.y * 64;
  __shared__ float t[64][65];
  int tx = threadIdx.x & 63, ty = threadIdx.x >> 6;
#pragma unroll
  for (int p = 0; p < 16; ++p) {
    int kr = p * 4 + ty;
    t[kr][tx] = W[(size_t)(k0 + kr) * 1024 + n0 + tx];
  }
  __syncthreads();
#pragma unroll
  for (int p = 0; p < 16; ++p) {
    int nr = p * 4 + ty;
    dst[(size_t)(n0 + nr) * 1024 + k0 + tx] = f2bf(t[tx][nr]);
  }
}

// ---------------- QKV projection GEMM ----------------
// grid (8, 32, 3): x = N-tile (128), y = M-tile (128), z = weight {q,k,v}
// z==0: out Q bf16 [bh][l][d] scaled by QSCALE; z==1: K bf16 [bh][l][d];
// z==2: out V^T bf16 [bh][d][l] via LDS-staged transpose epilogue.
__global__ __launch_bounds__(256) void qkv_gemm_kernel(
    const unsigned short* __restrict__ xb, const unsigned short* __restrict__ WtAll,
    const float* __restrict__ bq, const float* __restrict__ bk, const float* __restrict__ bv,
    unsigned short* __restrict__ qkv) {
  const int z = blockIdx.z;
  const unsigned short* Wt = WtAll + (size_t)z * 1024 * 1024;
  const float* bias = (z == 0) ? bq : (z == 1) ? bk : bv;
  unsigned short* outb = qkv + (size_t)z * 4194304;

  __shared__ __align__(16) unsigned short smem[128 * 72 * 2];
  unsigned short* As = smem;
  unsigned short* Bs = smem + 128 * 72;

  const int tid = threadIdx.x;
  const int w = tid >> 6, lane = tid & 63, g = lane >> 4, cc = lane & 15;
  const int wm = w >> 1, wn = w & 1;
  const int m0 = blockIdx.y * 128, n0 = blockIdx.x * 128;
  const int lr = tid >> 3, lc = (tid & 7) * 8;

  f32x4 acc[4][4];
#pragma unroll
  for (int i = 0; i < 4; ++i)
#pragma unroll
    for (int j = 0; j < 4; ++j) acc[i][j] = (f32x4)0.0f;

  for (int kk = 0; kk < 1024; kk += 64) {
    __syncthreads();
#pragma unroll
    for (int p = 0; p < 4; ++p) {
      int row = p * 32 + lr;
      *reinterpret_cast<uint4*>(&As[row * 72 + lc]) =
          *reinterpret_cast<const uint4*>(xb + (size_t)(m0 + row) * 1024 + kk + lc);
      *reinterpret_cast<uint4*>(&Bs[row * 72 + lc]) =
          *reinterpret_cast<const uint4*>(Wt + (size_t)(n0 + row) * 1024 + kk + lc);
    }
    __syncthreads();
    bf16x8 af[4][2], bfr[4][2];
#pragma unroll
    for (int mt = 0; mt < 4; ++mt)
#pragma unroll
      for (int ks = 0; ks < 2; ++ks)
        af[mt][ks] = ld_frag(&As[(wm * 64 + mt * 16 + cc) * 72 + ks * 32 + g * 8]);
#pragma unroll
    for (int nt = 0; nt < 4; ++nt)
#pragma unroll
      for (int ks = 0; ks < 2; ++ks)
        bfr[nt][ks] = ld_frag(&Bs[(wn * 64 + nt * 16 + cc) * 72 + ks * 32 + g * 8]);
#pragma unroll
    for (int mt = 0; mt < 4; ++mt)
#pragma unroll
      for (int nt = 0; nt < 4; ++nt)
#pragma unroll
        for (int ks = 0; ks < 2; ++ks)
          acc[mt][nt] = __builtin_amdgcn_mfma_f32_16x16x32_bf16(af[mt][ks], bfr[nt][ks],
                                                                acc[mt][nt], 0, 0, 0);
  }

  if (z != 2) {
    const float sc = (z == 0) ? QSCALE : 1.0f;
#pragma unroll
    for (int nt = 0; nt < 4; ++nt) {
      int n = n0 + wn * 64 + nt * 16 + cc;
      float bval = bias[n];
      int h = n >> 6, d = n & 63;
#pragma unroll
      for (int mt = 0; mt < 4; ++mt) {
#pragma unroll
        for (int r = 0; r < 4; ++r) {
          int m = m0 + wm * 64 + mt * 16 + g * 4 + r;
          int b = m >> 11, l = m & 2047;
          outb[(((size_t)(b * NHEADS + h) * LL) + l) * HDIM + d] =
              f2bf((acc[mt][nt][r] + bval) * sc);
        }
      }
    }
  } else {
    // V^T epilogue: stage C^T tile (n-major) in LDS, write [bh][d][l] coalesced
    __syncthreads();  // all frag reads of As/Bs done before overwrite
#pragma unroll
    for (int nt = 0; nt < 4; ++nt) {
      int nr = wn * 64 + nt * 16 + cc;
      float bval = bias[n0 + nr];
#pragma unroll
      for (int mt = 0; mt < 4; ++mt)
#pragma unroll
        for (int r = 0; r < 4; ++r)
          smem[nr * 136 + wm * 64 + mt * 16 + g * 4 + r] = f2bf(acc[mt][nt][r] + bval);
    }
    __syncthreads();
    int row = tid >> 1;                      // n-row in [0,128)
    int n = n0 + row, hh = n >> 6, dd = n & 63;
    int bb = m0 >> 11, l0 = (m0 & 2047) + (tid & 1) * 64;
    unsigned short* dst = outb + ((size_t)(bb * NHEADS + hh) * HDIM + dd) * LL + l0;
#pragma unroll
    for (int i = 0; i < 8; ++i)
      *reinterpret_cast<uint4*>(dst + i * 8) =
          *reinterpret_cast<const uint4*>(&smem[row * 136 + (tid & 1) * 64 + i * 8]);
  }
}

// ---------------- flash attention ----------------
// grid (16, 32): x = q-tile (128 rows), y = b*16+h. 4 waves; wave w owns q rows
// [w*32, w*32+32). No max-subtraction (logits bounded), no shuffles in the loop.
__global__ __launch_bounds__(256) void flash_kernel(
    const unsigned short* __restrict__ Qb, const unsigned short* __restrict__ Kb,
    const unsigned short* __restrict__ Vt, const float* __restrict__ mask,
    float* __restrict__ out) {
  const int bh = blockIdx.y, b = bh >> 4, h = bh & 15;
  const int q0 = blockIdx.x * 128;
  const int tid = threadIdx.x, w = tid >> 6, lane = tid & 63, g = lane >> 4, cc = lane & 15;
  const size_t bhoff = (size_t)bh * LL * HDIM;

  __shared__ __align__(16) unsigned short Qs[128 * 72];  // Q tile; recycled as P
  __shared__ __align__(16) unsigned short Ks[64 * 72];   // K tile [key][d]
  __shared__ __align__(16) unsigned short Vs[64 * 72];   // V^T tile [d][key]

  const int lr = tid >> 3, lc = (tid & 7) * 8;
#pragma unroll
  for (int p = 0; p < 4; ++p) {
    int row = p * 32 + lr;
    *reinterpret_cast<uint4*>(&Qs[row * 72 + lc]) =
        *reinterpret_cast<const uint4*>(Qb + bhoff + (size_t)(q0 + row) * HDIM + lc);
  }
  __syncthreads();
  bf16x8 aq[2][2];
#pragma unroll
  for (int mt = 0; mt < 2; ++mt)
#pragma unroll
    for (int ks = 0; ks < 2; ++ks)
      aq[mt][ks] = ld_frag(&Qs[(w * 32 + mt * 16 + cc) * 72 + ks * 32 + g * 8]);

  float li[2][4];
  f32x4 oacc[2][4];
#pragma unroll
  for (int mt = 0; mt < 2; ++mt) {
#pragma unroll
    for (int r = 0; r < 4; ++r) li[mt][r] = 0.0f;
#pragma unroll
    for (int nt = 0; nt < 4; ++nt) oacc[mt][nt] = (f32x4)0.0f;
  }

  const float* mbase = mask + ((size_t)b * LL + q0 + w * 32) * LL + cc;

  for (int kt = 0; kt < 32; ++kt) {
    // prefetch mask tile values for this wave's 8 row-groups x 4 col-groups
    float mv[2][4][4];
#pragma unroll
    for (int mt = 0; mt < 2; ++mt)
#pragma unroll
      for (int r = 0; r < 4; ++r) {
        const float* mrow = mbase + (size_t)(mt * 16 + g * 4 + r) * LL + kt * 64;
#pragma unroll
        for (int nt = 0; nt < 4; ++nt) mv[mt][r][nt] = mrow[nt * 16];
      }

    __syncthreads();  // previous iteration's K/V frag reads done
#pragma unroll
    for (int p = 0; p < 2; ++p) {
      int row = p * 32 + lr;
      *reinterpret_cast<uint4*>(&Ks[row * 72 + lc]) =
          *reinterpret_cast<const uint4*>(Kb + bhoff + (size_t)(kt * 64 + row) * HDIM + lc);
      *reinterpret_cast<uint4*>(&Vs[row * 72 + lc]) =
          *reinterpret_cast<const uint4*>(Vt + bhoff + (size_t)row * LL + kt * 64 + lc);
    }
    __syncthreads();

    // S = Q @ K^T
    bf16x8 bk_[4][2];
#pragma unroll
    for (int nt = 0; nt < 4; ++nt)
#pragma unroll
      for (int ks = 0; ks < 2; ++ks)
        bk_[nt][ks] = ld_frag(&Ks[(nt * 16 + cc) * 72 + ks * 32 + g * 8]);
    f32x4 sacc[2][4];
#pragma unroll
    for (int mt = 0; mt < 2; ++mt)
#pragma unroll
      for (int nt = 0; nt < 4; ++nt) sacc[mt][nt] = (f32x4)0.0f;
#pragma unroll
    for (int mt = 0; mt < 2; ++mt)
#pragma unroll
      for (int nt = 0; nt < 4; ++nt)
#pragma unroll
        for (int ks = 0; ks < 2; ++ks)
          sacc[mt][nt] = __builtin_amdgcn_mfma_f32_16x16x32_bf16(aq[mt][ks], bk_[nt][ks],
                                                                 sacc[mt][nt], 0, 0, 0);

    // p = exp2(sacc + mask*MASKC1); no max-sub, no shuffles; P -> recycled Qs (wave-private rows)
#pragma unroll
    for (int mt = 0; mt < 2; ++mt) {
#pragma unroll
      for (int r = 0; r < 4; ++r) {
        int prow = (w * 32 + mt * 16 + g * 4 + r) * 72 + cc;
        float p0 = __builtin_amdgcn_exp2f(fmaf(mv[mt][r][0], MASKC1, sacc[mt][0][r]));
        float p1 = __builtin_amdgcn_exp2f(fmaf(mv[mt][r][1], MASKC1, sacc[mt][1][r]));
        float p2 = __builtin_amdgcn_exp2f(fmaf(mv[mt][r][2], MASKC1, sacc[mt][2][r]));
        float p3 = __builtin_amdgcn_exp2f(fmaf(mv[mt][r][3], MASKC1, sacc[mt][3][r]));
        li[mt][r] += (p0 + p1) + (p2 + p3);
        Qs[prow]      = f2bf(p0);
        Qs[prow + 16] = f2bf(p1);
        Qs[prow + 32] = f2bf(p2);
        Qs[prow + 48] = f2bf(p3);
      }
    }
    asm volatile("" ::: "memory");  // P stores before P frag reads (same-wave DS order)

    // O += P @ V
    bf16x8 ap[2][2], bv[4][2];
#pragma unroll
    for (int mt = 0; mt < 2; ++mt)
#pragma unroll
      for (int ks = 0; ks < 2; ++ks)
        ap[mt][ks] = ld_frag(&Qs[(w * 32 + mt * 16 + cc) * 72 + ks * 32 + g * 8]);
#pragma unroll
    for (int nt = 0; nt < 4; ++nt)
#pragma unroll
      for (int ks = 0; ks < 2; ++ks)
        bv[nt][ks] = ld_frag(&Vs[(nt * 16 + cc) * 72 + ks * 32 + g * 8]);
#pragma unroll
    for (int mt = 0; mt < 2; ++mt)
#pragma unroll
      for (int nt = 0; nt < 4; ++nt)
#pragma unroll
        for (int ks = 0; ks < 2; ++ks)
          oacc[mt][nt] = __builtin_amdgcn_mfma_f32_16x16x32_bf16(ap[mt][ks], bv[nt][ks],
                                                                 oacc[mt][nt], 0, 0, 0);
  }

  // epilogue: one li reduction per row, normalize, write [B, L, H*HD] fp32
#pragma unroll
  for (int mt = 0; mt < 2; ++mt)
#pragma unroll
    for (int r = 0; r < 4; ++r) {
      float s = li[mt][r];
      s += __shfl_xor(s, 1);
      s += __shfl_xor(s, 2);
      s += __shfl_xor(s, 4);
      s += __shfl_xor(s, 8);
      float inv = 1.0f / s;
      int qrow = q0 + w * 32 + mt * 16 + g * 4 + r;
#pragma unroll
      for (int nt = 0; nt < 4; ++nt)
        out[((size_t)b * LL + qrow) * 1024 + h * 64 + nt * 16 + cc] = oacc[mt][nt][r] * inv;
    }
}

extern "C" void kernel_launch(void* const* d_in, const int* in_sizes, int n_in,
                              void* d_out, int out_size, void* d_ws, size_t ws_size,
                              hipStream_t stream) {
  const float* x    = (const float*)d_in[0];
  const float* mask = (const float*)d_in[1];
  const float* Wq   = (const float*)d_in[2];
  const float* bq   = (const float*)d_in[3];
  const float* Wk   = (const float*)d_in[4];
  const float* bk   = (const float*)d_in[5];
  const float* Wv   = (const float*)d_in[6];
  const float* bv   = (const float*)d_in[7];
  float* out = (float*)d_out;

  char* ws = (char*)d_ws;
  unsigned short* xb  = (unsigned short*)(ws);                 // 8 MiB: x bf16 [4096][1024]
  unsigned short* Wt  = (unsigned short*)(ws + (8u << 20));    // 6 MiB: Wq,Wk,Wv transposed bf16
  unsigned short* qkv = (unsigned short*)(ws + (14u << 20));   // 24 MiB: Q,K bf16 [bh][l][d]; V^T [bh][d][l]

  cvt_x_kernel<<<dim3(4096), dim3(256), 0, stream>>>(x, xb);
  transpose_w_kernel<<<dim3(16, 16, 3), dim3(256), 0, stream>>>(Wq, Wk, Wv, Wt);
  qkv_gemm_kernel<<<dim3(8, 32, 3), dim3(256), 0, stream>>>(xb, Wt, bq, bk, bv, qkv);
  flash_kernel<<<dim3(16, 32), dim3(256), 0, stream>>>(qkv, qkv + 4194304, qkv + 8388608,
                                                       mask, out);
}

// Round 3
// 214.875 us; speedup vs baseline: 1.3802x; 1.1786x over previous
//
#include <hip/hip_runtime.h>

// B=2, L=2048, DIM=1024, H=16, HD=64; scale folded into Q: 0.125*log2e; mask: -60*log2e
#define LL 2048
#define NHEADS 16
#define HDIM 64
#define QSCALE 0.18033688011112042f   // 0.125 * log2(e)
#define MASKC1 -86.56170245333780f    // -60 * log2(e)

typedef __attribute__((ext_vector_type(8))) __bf16 bf16x8;
typedef __attribute__((ext_vector_type(4))) float f32x4;

__device__ __forceinline__ unsigned short f2bf(float f) {
  unsigned int u = __builtin_bit_cast(unsigned int, f);
  u += 0x7fffu + ((u >> 16) & 1u);   // RNE
  return (unsigned short)(u >> 16);
}

__device__ __forceinline__ bf16x8 ld_frag(const unsigned short* p) {
  return *reinterpret_cast<const bf16x8*>(p);
}

// async global->LDS, 16B per lane; LDS dest = wave-uniform base + lane*16
__device__ __forceinline__ void async_cp16(const unsigned short* g, unsigned short* l) {
  __builtin_amdgcn_global_load_lds(
      (const __attribute__((address_space(1))) unsigned int*)(unsigned long long)(g),
      (__attribute__((address_space(3))) unsigned int*)(unsigned int)(unsigned long long)(l),
      16, 0, 0);
}

// ---------------- prep: fp32 -> bf16 convert of x ----------------
__global__ __launch_bounds__(256) void cvt_x_kernel(const float* __restrict__ x,
                                                    unsigned short* __restrict__ xb) {
  int i = (blockIdx.x * 256 + threadIdx.x) * 4;
  float4 v = *reinterpret_cast<const float4*>(x + i);
  ushort4 o;
  o.x = f2bf(v.x); o.y = f2bf(v.y); o.z = f2bf(v.z); o.w = f2bf(v.w);
  *reinterpret_cast<ushort4*>(xb + i) = o;
}

// ---------------- prep: W [K][N] fp32 -> Wt [N][K] bf16 ----------------
__global__ __launch_bounds__(256) void transpose_w_kernel(const float* __restrict__ Wq,
                                                          const float* __restrict__ Wk,
                                                          const float* __restrict__ Wv,
                                                          unsigned short* __restrict__ WtAll) {
  int z = blockIdx.z;
  const float* W = (z == 0) ? Wq : (z == 1) ? Wk : Wv;
  unsigned short* dst = WtAll + (size_t)z * 1024 * 1024;
  int n0 = blockIdx.x * 64, k0 = blockIdx.y * 64;
  __shared__ float t[64][65];
  int tx = threadIdx.x & 63, ty = threadIdx.x >> 6;
#pragma unroll
  for (int p = 0; p < 16; ++p) {
    int kr = p * 4 + ty;
    t[kr][tx] = W[(size_t)(k0 + kr) * 1024 + n0 + tx];
  }
  __syncthreads();
#pragma unroll
  for (int p = 0; p < 16; ++p) {
    int nr = p * 4 + ty;
    dst[(size_t)(n0 + nr) * 1024 + k0 + tx] = f2bf(t[tx][nr]);
  }
}

// ---------------- prep: em = bf16(exp2(mask*MASKC1)), key-permuted pos=4c+q ----------------
// grid (2, 4096): row = b*L+q; thread handles one (kb, c): reads cols kb*64+c+16q (q=0..3),
// writes ushort4 at kb*64+4c.
__global__ __launch_bounds__(256) void em_prep_kernel(const float* __restrict__ mask,
                                                      unsigned short* __restrict__ em) {
  int row = blockIdx.y;
  int t = blockIdx.x * 256 + threadIdx.x;
  int kb = t >> 4, c = t & 15;
  const float* src = mask + (size_t)row * LL + kb * 64 + c;
  ushort4 o;
  o.x = f2bf(__builtin_amdgcn_exp2f(src[0]  * MASKC1));
  o.y = f2bf(__builtin_amdgcn_exp2f(src[16] * MASKC1));
  o.z = f2bf(__builtin_amdgcn_exp2f(src[32] * MASKC1));
  o.w = f2bf(__builtin_amdgcn_exp2f(src[48] * MASKC1));
  *reinterpret_cast<ushort4*>(em + (size_t)row * LL + kb * 64 + 4 * c) = o;
}

// ---------------- QKV projection GEMM (m97-style async staging, swizzled rows) ----------------
// grid (8, 32, 3). z==0: Q bf16 [bh][l][d] * QSCALE; z==1: K; z==2: V^T [bh][d][l], pos-permuted.
__global__ __launch_bounds__(256) void qkv_gemm_kernel(
    const unsigned short* __restrict__ xb, const unsigned short* __restrict__ WtAll,
    const float* __restrict__ bq, const float* __restrict__ bk, const float* __restrict__ bv,
    unsigned short* __restrict__ qkv) {
  const int z = blockIdx.z;
  const unsigned short* Wt = WtAll + (size_t)z * 1024 * 1024;
  const float* bias = (z == 0) ? bq : (z == 1) ? bk : bv;
  unsigned short* outb = qkv + (size_t)z * 4194304;

  __shared__ __align__(16) unsigned short smem[16384];  // As 8192, Bs 8192 (stride 64, swizzled)
  unsigned short* As = smem;
  unsigned short* Bs = smem + 8192;

  const int tid = threadIdx.x;
  const int w = tid >> 6, lane = tid & 63, g = lane >> 4, cc = lane & 15;
  const int wm = w >> 1, wn = w & 1;
  const int m0 = blockIdx.y * 128, n0 = blockIdx.x * 128;
  // async staging: wave w stages A/B rows [w*32, w*32+32) as 4 segs of 8 rows.
  const int srow = lane >> 3;                 // row within seg
  const int gc = ((lane & 7) - srow) & 7;     // swizzle: LDS slot s holds chunk (s - row)&7
  const unsigned short* ga = xb + (size_t)(m0 + w * 32 + srow) * 1024 + gc * 8;
  const unsigned short* gb = Wt + (size_t)(n0 + w * 32 + srow) * 1024 + gc * 8;
  unsigned short* la = As + w * 2048;   // 4 segs * 512
  unsigned short* lb = Bs + w * 2048;

  f32x4 acc[4][4];
#pragma unroll
  for (int i = 0; i < 4; ++i)
#pragma unroll
    for (int j = 0; j < 4; ++j) acc[i][j] = (f32x4)0.0f;

  for (int kk = 0; kk < 1024; kk += 64) {
    __syncthreads();
#pragma unroll
    for (int i = 0; i < 4; ++i) {
      async_cp16(ga + i * 8192 + kk, la + i * 512);
      async_cp16(gb + i * 8192 + kk, lb + i * 512);
    }
    __syncthreads();  // compiler emits vmcnt(0) drain before barrier
    bf16x8 af[4][2], bfr[4][2];
#pragma unroll
    for (int mt = 0; mt < 4; ++mt)
#pragma unroll
      for (int ks = 0; ks < 2; ++ks)
        af[mt][ks] = ld_frag(&As[(wm * 64 + mt * 16 + cc) * 64 + ((4 * ks + g + cc) & 7) * 8]);
#pragma unroll
    for (int nt = 0; nt < 4; ++nt)
#pragma unroll
      for (int ks = 0; ks < 2; ++ks)
        bfr[nt][ks] = ld_frag(&Bs[(wn * 64 + nt * 16 + cc) * 64 + ((4 * ks + g + cc) & 7) * 8]);
#pragma unroll
    for (int mt = 0; mt < 4; ++mt)
#pragma unroll
      for (int nt = 0; nt < 4; ++nt)
#pragma unroll
        for (int ks = 0; ks < 2; ++ks)
          acc[mt][nt] = __builtin_amdgcn_mfma_f32_16x16x32_bf16(af[mt][ks], bfr[nt][ks],
                                                                acc[mt][nt], 0, 0, 0);
  }

  if (z != 2) {
    const float sc = (z == 0) ? QSCALE : 1.0f;
#pragma unroll
    for (int nt = 0; nt < 4; ++nt) {
      int n = n0 + wn * 64 + nt * 16 + cc;
      float bval = bias[n];
      int h = n >> 6, d = n & 63;
#pragma unroll
      for (int mt = 0; mt < 4; ++mt) {
#pragma unroll
        for (int r = 0; r < 4; ++r) {
          int m = m0 + wm * 64 + mt * 16 + g * 4 + r;
          int b = m >> 11, l = m & 2047;
          outb[(((size_t)(b * NHEADS + h) * LL) + l) * HDIM + d] =
              f2bf((acc[mt][nt][r] + bval) * sc);
        }
      }
    }
  } else {
    // V^T epilogue with key permutation pos = 4c + q (c = local&15, q = local>>4):
    // local = mt*16 + g*4 + r  ->  pos = 16g + 4r + mt
    __syncthreads();
#pragma unroll
    for (int nt = 0; nt < 4; ++nt) {
      int nr = wn * 64 + nt * 16 + cc;
      float bval = bias[n0 + nr];
#pragma unroll
      for (int mt = 0; mt < 4; ++mt)
#pragma unroll
        for (int r = 0; r < 4; ++r)
          smem[nr * 128 + wm * 64 + 16 * g + 4 * r + mt] = f2bf(acc[mt][nt][r] + bval);
    }
    __syncthreads();
    int row = tid >> 1, half = tid & 1;
    int n = n0 + row, hh = n >> 6, dd = n & 63;
    int bb = m0 >> 11, l0 = (m0 & 2047) + half * 64;
    unsigned short* dst = outb + ((size_t)(bb * NHEADS + hh) * HDIM + dd) * LL + l0;
#pragma unroll
    for (int i = 0; i < 8; ++i)
      *reinterpret_cast<uint4*>(dst + i * 8) =
          *reinterpret_cast<const uint4*>(&smem[row * 128 + half * 64 + i * 8]);
  }
}

// ---------------- flash attention ----------------
// grid (16, 32). One barrier/kt: ping-pong K/V tiles via global_load_lds (swizzled rows);
// Q frags direct from global; P packed b64 (pos-permuted keys); em bf16 vectorized.
__global__ __launch_bounds__(256) void flash_kernel(
    const unsigned short* __restrict__ Qb, const unsigned short* __restrict__ Kb,
    const unsigned short* __restrict__ Vt, const unsigned short* __restrict__ Em,
    float* __restrict__ out) {
  const int bh = blockIdx.y, b = bh >> 4, h = bh & 15;
  const int q0 = blockIdx.x * 128;
  const int tid = threadIdx.x, w = tid >> 6, lane = tid & 63, g = lane >> 4, cc = lane & 15;
  const size_t bhoff = (size_t)bh * LL * HDIM;

  __shared__ __align__(16) unsigned short Ps[128 * 72];      // P tile, stride 72, pos-ordered
  __shared__ __align__(16) unsigned short Ks[2][64 * 64];    // [key][d], swizzled chunks
  __shared__ __align__(16) unsigned short Vs[2][64 * 64];    // [d][pos], swizzled chunks

  // Q fragments straight from global (loop-invariant)
  bf16x8 aq[2][2];
#pragma unroll
  for (int mt = 0; mt < 2; ++mt)
#pragma unroll
    for (int ks = 0; ks < 2; ++ks)
      aq[mt][ks] = *reinterpret_cast<const bf16x8*>(
          Qb + bhoff + (size_t)(q0 + w * 32 + mt * 16 + cc) * HDIM + ks * 32 + g * 8);

  // async staging: wave w stages K segs {w, w+4} and V segs {w, w+4}
  const int srow = lane >> 3;
  const int gcs = ((lane & 7) - srow) & 7;
  const unsigned short* kg0 = Kb + bhoff + (size_t)(w * 8 + srow) * HDIM + gcs * 8;
  const unsigned short* kg1 = Kb + bhoff + (size_t)(32 + w * 8 + srow) * HDIM + gcs * 8;
  const unsigned short* vg0 = Vt + bhoff + (size_t)(w * 8 + srow) * LL + gcs * 8;
  const unsigned short* vg1 = Vt + bhoff + (size_t)(32 + w * 8 + srow) * LL + gcs * 8;

  float li[2][4];
  f32x4 oacc[2][4];
#pragma unroll
  for (int mt = 0; mt < 2; ++mt) {
#pragma unroll
    for (int r = 0; r < 4; ++r) li[mt][r] = 0.0f;
#pragma unroll
    for (int nt = 0; nt < 4; ++nt) oacc[mt][nt] = (f32x4)0.0f;
  }

  const unsigned short* embase = Em + ((size_t)b * LL + q0 + w * 32) * LL + 4 * cc;

  // stage tile 0 into buf 0
  {
    async_cp16(kg0, Ks[0] + w * 512);
    async_cp16(kg1, Ks[0] + (w + 4) * 512);
    async_cp16(vg0, Vs[0] + w * 512);
    async_cp16(vg1, Vs[0] + (w + 4) * 512);
  }

  for (int kt = 0; kt < 32; ++kt) {
    const int buf = kt & 1;
    __syncthreads();  // drains own asyncs (vmcnt 0) -> tile kt ready; prior reads of buf^1 done
    if (kt + 1 < 32) {
      const int nb = buf ^ 1;
      async_cp16(kg0 + (size_t)(kt + 1) * 64 * HDIM, Ks[nb] + w * 512);
      async_cp16(kg1 + (size_t)(kt + 1) * 64 * HDIM, Ks[nb] + (w + 4) * 512);
      async_cp16(vg0 + (kt + 1) * 64, Vs[nb] + w * 512);
      async_cp16(vg1 + (kt + 1) * 64, Vs[nb] + (w + 4) * 512);
    }
    // em loads: ushort4 per (mt,r), pos 4cc..4cc+3  <->  nt 0..3
    uint2 emv[2][4];
#pragma unroll
    for (int mt = 0; mt < 2; ++mt)
#pragma unroll
      for (int r = 0; r < 4; ++r)
        emv[mt][r] = *reinterpret_cast<const uint2*>(
            embase + (size_t)(mt * 16 + g * 4 + r) * LL + kt * 64);

    // S = Q @ K^T
    bf16x8 bk_[4][2];
#pragma unroll
    for (int nt = 0; nt < 4; ++nt)
#pragma unroll
      for (int ks = 0; ks < 2; ++ks)
        bk_[nt][ks] =
            ld_frag(&Ks[buf][(nt * 16 + cc) * 64 + ((4 * ks + g + cc) & 7) * 8]);
    f32x4 sacc[2][4];
#pragma unroll
    for (int mt = 0; mt < 2; ++mt)
#pragma unroll
      for (int nt = 0; nt < 4; ++nt) sacc[mt][nt] = (f32x4)0.0f;
#pragma unroll
    for (int mt = 0; mt < 2; ++mt)
#pragma unroll
      for (int nt = 0; nt < 4; ++nt)
#pragma unroll
        for (int ks = 0; ks < 2; ++ks)
          sacc[mt][nt] = __builtin_amdgcn_mfma_f32_16x16x32_bf16(aq[mt][ks], bk_[nt][ks],
                                                                 sacc[mt][nt], 0, 0, 0);

    // p = exp2(s) * em; pack 4 bf16 (truncation) -> one b64 store at pos 4cc
#pragma unroll
    for (int mt = 0; mt < 2; ++mt) {
#pragma unroll
      for (int r = 0; r < 4; ++r) {
        unsigned int ex = emv[mt][r].x, ey = emv[mt][r].y;
        float e0 = __builtin_bit_cast(float, ex << 16);
        float e1 = __builtin_bit_cast(float, ex & 0xffff0000u);
        float e2 = __builtin_bit_cast(float, ey << 16);
        float e3 = __builtin_bit_cast(float, ey & 0xffff0000u);
        float p0 = __builtin_amdgcn_exp2f(sacc[mt][0][r]) * e0;
        float p1 = __builtin_amdgcn_exp2f(sacc[mt][1][r]) * e1;
        float p2 = __builtin_amdgcn_exp2f(sacc[mt][2][r]) * e2;
        float p3 = __builtin_amdgcn_exp2f(sacc[mt][3][r]) * e3;
        unsigned int u01 = __builtin_amdgcn_perm(__builtin_bit_cast(unsigned int, p1),
                                                 __builtin_bit_cast(unsigned int, p0),
                                                 0x07060302u);
        unsigned int u23 = __builtin_amdgcn_perm(__builtin_bit_cast(unsigned int, p3),
                                                 __builtin_bit_cast(unsigned int, p2),
                                                 0x07060302u);
        // li sums the truncated values so numerator/denominator stay consistent
        li[mt][r] += __builtin_bit_cast(float, u01 << 16) +
                     __builtin_bit_cast(float, u01 & 0xffff0000u) +
                     __builtin_bit_cast(float, u23 << 16) +
                     __builtin_bit_cast(float, u23 & 0xffff0000u);
        uint2 pk; pk.x = u01; pk.y = u23;
        *reinterpret_cast<uint2*>(&Ps[(w * 32 + mt * 16 + g * 4 + r) * 72 + 4 * cc]) = pk;
      }
    }
    asm volatile("" ::: "memory");  // P stores before same-wave P frag reads

    // O += P @ V   (k-dim = pos, matches Vs column order)
    bf16x8 ap[2][2], bv[4][2];
#pragma unroll
    for (int mt = 0; mt < 2; ++mt)
#pragma unroll
      for (int ks = 0; ks < 2; ++ks)
        ap[mt][ks] = ld_frag(&Ps[(w * 32 + mt * 16 + cc) * 72 + ks * 32 + g * 8]);
#pragma unroll
    for (int nt = 0; nt < 4; ++nt)
#pragma unroll
      for (int ks = 0; ks < 2; ++ks)
        bv[nt][ks] =
            ld_frag(&Vs[buf][(nt * 16 + cc) * 64 + ((4 * ks + g + cc) & 7) * 8]);
#pragma unroll
    for (int mt = 0; mt < 2; ++mt)
#pragma unroll
      for (int nt = 0; nt < 4; ++nt)
#pragma unroll
        for (int ks = 0; ks < 2; ++ks)
          oacc[mt][nt] = __builtin_amdgcn_mfma_f32_16x16x32_bf16(ap[mt][ks], bv[nt][ks],
                                                                 oacc[mt][nt], 0, 0, 0);
  }

  // epilogue: reduce li over cc-lanes, normalize, write [B, L, H*HD] fp32
#pragma unroll
  for (int mt = 0; mt < 2; ++mt)
#pragma unroll
    for (int r = 0; r < 4; ++r) {
      float s = li[mt][r];
      s += __shfl_xor(s, 1);
      s += __shfl_xor(s, 2);
      s += __shfl_xor(s, 4);
      s += __shfl_xor(s, 8);
      float inv = 1.0f / s;
      int qrow = q0 + w * 32 + mt * 16 + g * 4 + r;
#pragma unroll
      for (int nt = 0; nt < 4; ++nt)
        out[((size_t)b * LL + qrow) * 1024 + h * 64 + nt * 16 + cc] = oacc[mt][nt][r] * inv;
    }
}

extern "C" void kernel_launch(void* const* d_in, const int* in_sizes, int n_in,
                              void* d_out, int out_size, void* d_ws, size_t ws_size,
                              hipStream_t stream) {
  const float* x    = (const float*)d_in[0];
  const float* mask = (const float*)d_in[1];
  const float* Wq   = (const float*)d_in[2];
  const float* bq   = (const float*)d_in[3];
  const float* Wk   = (const float*)d_in[4];
  const float* bk   = (const float*)d_in[5];
  const float* Wv   = (const float*)d_in[6];
  const float* bv   = (const float*)d_in[7];
  float* out = (float*)d_out;
  (void)in_sizes; (void)n_in; (void)out_size; (void)ws_size;

  char* ws = (char*)d_ws;
  // layout: qkv @0 (24 MiB); xb @24 (8 MiB); Wt @32 (6 MiB);
  // em @24 (16 MiB) overlaps xb/Wt — dead after qkv_gemm (same-stream serialization)
  unsigned short* qkv = (unsigned short*)(ws);
  unsigned short* xb  = (unsigned short*)(ws + (24u << 20));
  unsigned short* Wt  = (unsigned short*)(ws + (32u << 20));
  unsigned short* em  = (unsigned short*)(ws + (24u << 20));

  cvt_x_kernel<<<dim3(4096), dim3(256), 0, stream>>>(x, xb);
  transpose_w_kernel<<<dim3(16, 16, 3), dim3(256), 0, stream>>>(Wq, Wk, Wv, Wt);
  qkv_gemm_kernel<<<dim3(8, 32, 3), dim3(256), 0, stream>>>(xb, Wt, bq, bk, bv, qkv);
  em_prep_kernel<<<dim3(2, 4096), dim3(256), 0, stream>>>(mask, em);
  flash_kernel<<<dim3(16, 32), dim3(256), 0, stream>>>(qkv, qkv + 4194304, qkv + 8388608,
                                                       em, out);
}